// Round 2
// baseline (194.688 us; speedup 1.0000x reference)
//
#include <hip/hip_runtime.h>

// Problem constants
#define H_ROWS 4096
#define IN_F   4096
#define OUT_F  4096

typedef __bf16 bf16;
typedef __bf16 bf16x4 __attribute__((ext_vector_type(4)));
typedef __bf16 bf16x8 __attribute__((ext_vector_type(8)));
typedef float  f32x4  __attribute__((ext_vector_type(4)));

// ---------------------------------------------------------------------------
// Kernel 1: fused reductions.
//   blocks 0..1023   : xs[h][t]  = sum_{v=0..15} x[h][v*256 + t]        (t<256)
//   blocks 1024..2047: wsT[o][t] = sum_{i=0..15} weight[o][i*256 + t]
// R2 fix: explicit 16-wide load batch (all loads issued before any use) so
// 16 dwordx4 stay in flight per thread (R1 had VGPR=32 -> serialized, 1.2TB/s).
// Load order rotated by row&15 (wave-uniform) to spread HBM channel traffic.
// ---------------------------------------------------------------------------
__global__ __launch_bounds__(256) void reduce_kernel(
    const float* __restrict__ x, const float* __restrict__ w,
    bf16* __restrict__ xs, bf16* __restrict__ wsT)
{
    const int bid = blockIdx.x;
    const float* src = (bid & 1024) ? w : x;
    bf16* dst = (bid & 1024) ? wsT : xs;
    const int gid = (bid & 1023) * 256 + threadIdx.x;   // 0..262143
    const int row = gid >> 6;                            // 0..4095 (wave-uniform)
    const int t4  = gid & 63;                            // float4 index (= lane)

    const float4* s = (const float4*)src + row * (IN_F / 4) + t4;
    const int r0 = row & 15;                             // wave-uniform rotation

    float4 b[16];
    #pragma unroll
    for (int v = 0; v < 16; ++v) {
        const int vv = (v + r0) & 15;
        b[v] = s[vv * 64];
    }
    float4 a = b[0];
    #pragma unroll
    for (int v = 1; v < 16; ++v) {
        a.x += b[v].x; a.y += b[v].y; a.z += b[v].z; a.w += b[v].w;
    }
    bf16x4 o;
    o[0] = (bf16)a.x; o[1] = (bf16)a.y; o[2] = (bf16)a.z; o[3] = (bf16)a.w;
    *(bf16x4*)(dst + row * 256 + t4 * 4) = o;
}

// ---------------------------------------------------------------------------
// Kernel 2: NT GEMM  out[m][n] = sum_k A[m][k]*B[n][k] + bias[n]
//   A = xs  (M=4096, K=256) bf16 row-major
//   B = wsT (N=4096, K=256) bf16 row-major
// m97 structure: 128x128 block tile, BK=32, global_load_lds width=16,
// 4 waves in 2x2, each wave 64x64 = 4x4 tiles of 16x16x32 MFMA.
// ---------------------------------------------------------------------------
__global__ __launch_bounds__(256) void gemm_bt_kernel(
    const bf16* __restrict__ A, const bf16* __restrict__ B,
    const float* __restrict__ bias, float* __restrict__ out)
{
    __shared__ bf16 As[128 * 32];   // 8 KB
    __shared__ bf16 Bs[128 * 32];   // 8 KB

    const int m0   = blockIdx.y * 128;
    const int n0   = blockIdx.x * 128;
    const int tid  = threadIdx.x;
    const int lane = tid & 63;
    const int w    = tid >> 6;
    const int wm   = (w & 1) * 64;
    const int wn   = (w >> 1) * 64;
    const int l15  = lane & 15;
    const int quad = lane >> 4;

    f32x4 acc[4][4] = {};

    for (int kk = 0; kk < 8; ++kk) {
        const int k0 = kk * 32;
        #pragma unroll
        for (int c = 0; c < 2; ++c) {
            const int chunk = c * 256 + tid;
            const int row   = chunk >> 2;      // 0..127
            const int kc    = chunk & 3;       // 16B chunk within 64B row
            const bf16* ga = A + (m0 + row) * 256 + k0 + kc * 8;
            const bf16* gb = B + (n0 + row) * 256 + k0 + kc * 8;
            __builtin_amdgcn_global_load_lds(
                (const __attribute__((address_space(1))) void*)ga,
                (__attribute__((address_space(3))) void*)(As + chunk * 8), 16, 0, 0);
            __builtin_amdgcn_global_load_lds(
                (const __attribute__((address_space(1))) void*)gb,
                (__attribute__((address_space(3))) void*)(Bs + chunk * 8), 16, 0, 0);
        }
        __syncthreads();

        bf16x8 af[4], bfr[4];
        #pragma unroll
        for (int t = 0; t < 4; ++t) {
            af[t]  = *(const bf16x8*)(As + (wm + t * 16 + l15) * 32 + quad * 8);
            bfr[t] = *(const bf16x8*)(Bs + (wn + t * 16 + l15) * 32 + quad * 8);
        }
        #pragma unroll
        for (int mt = 0; mt < 4; ++mt)
            #pragma unroll
            for (int nt = 0; nt < 4; ++nt)
                acc[mt][nt] = __builtin_amdgcn_mfma_f32_16x16x32_bf16(
                    af[mt], bfr[nt], acc[mt][nt], 0, 0, 0);
        __syncthreads();
    }

    #pragma unroll
    for (int nt = 0; nt < 4; ++nt) {
        const int col = n0 + wn + nt * 16 + l15;
        const float bv = bias[col];
        #pragma unroll
        for (int mt = 0; mt < 4; ++mt) {
            const int rbase = m0 + wm + mt * 16 + quad * 4;
            #pragma unroll
            for (int r = 0; r < 4; ++r)
                out[(rbase + r) * OUT_F + col] = acc[mt][nt][r] + bv;
        }
    }
}

extern "C" void kernel_launch(void* const* d_in, const int* in_sizes, int n_in,
                              void* d_out, int out_size, void* d_ws, size_t ws_size,
                              hipStream_t stream)
{
    const float* x      = (const float*)d_in[0];  // (4096, 4096)
    const float* weight = (const float*)d_in[1];  // (4096, 4096)
    const float* bias   = (const float*)d_in[2];  // (4096,)
    float* out = (float*)d_out;                   // (4096, 4096) f32

    bf16* xs  = (bf16*)d_ws;                      // 4096*256 bf16 = 2 MB
    bf16* wsT = xs + 4096 * 256;                  // 4096*256 bf16 = 2 MB

    reduce_kernel<<<2048, 256, 0, stream>>>(x, weight, xs, wsT);
    gemm_bt_kernel<<<dim3(32, 32), 256, 0, stream>>>(xs, wsT, bias, out);
}

// Round 3
// 189.747 us; speedup vs baseline: 1.0260x; 1.0260x over previous
//
#include <hip/hip_runtime.h>

// Problem constants
#define H_ROWS 4096
#define IN_F   4096
#define OUT_F  4096

typedef __bf16 bf16;
typedef __bf16 bf16x4 __attribute__((ext_vector_type(4)));
typedef __bf16 bf16x8 __attribute__((ext_vector_type(8)));
typedef float  f32x4  __attribute__((ext_vector_type(4)));

// ---------------------------------------------------------------------------
// Kernel 1 (R3 rewrite): one block per matrix row, pure streaming reads.
//   block bid: row r = bid>>1 of (bid&1 ? weight : x).
//   xs[r][t] = sum_{v} x[r][v*256+t]. Element j of the row maps to t = j&255;
//   float4 index f maps to t4 = f&63, so a thread reading f = tid, tid+256,
//   tid+512, tid+768 accumulates one t-group in a single float4 register
//   (4 independent contiguous 4KB sweeps -> streaming like the copy bench).
//   Cross-thread finish: 4KB LDS tree over the 4 thread-groups (free 2-way
//   bank aliasing on b128), then 64 threads store bf16x4.
// R1/R2 lesson: per-wave ILP tweaks did nothing (57us pinned, 1.25 TB/s);
// the strided 1KB-burst shape + 8 blocks/CU with no backfill was the limiter.
// ---------------------------------------------------------------------------
__global__ __launch_bounds__(256) void reduce_kernel(
    const float* __restrict__ x, const float* __restrict__ w,
    bf16* __restrict__ xs, bf16* __restrict__ wsT)
{
    __shared__ float lds[1024];
    const int bid = blockIdx.x;
    const float* __restrict__ src = (bid & 1) ? w : x;
    bf16* __restrict__ dst = (bid & 1) ? wsT : xs;
    const int r   = bid >> 1;            // row 0..4095
    const int tid = threadIdx.x;

    const float4* __restrict__ s = (const float4*)src + r * (IN_F / 4);
    float4 a0 = s[tid];
    float4 a1 = s[tid + 256];
    float4 a2 = s[tid + 512];
    float4 a3 = s[tid + 768];
    float4 acc;
    acc.x = (a0.x + a1.x) + (a2.x + a3.x);
    acc.y = (a0.y + a1.y) + (a2.y + a3.y);
    acc.z = (a0.z + a1.z) + (a2.z + a3.z);
    acc.w = (a0.w + a1.w) + (a2.w + a3.w);

    ((float4*)lds)[tid] = acc;
    __syncthreads();

    if (tid < 64) {
        float4 b0 = ((const float4*)lds)[tid];
        float4 b1 = ((const float4*)lds)[tid + 64];
        float4 b2 = ((const float4*)lds)[tid + 128];
        float4 b3 = ((const float4*)lds)[tid + 192];
        float4 t;
        t.x = (b0.x + b1.x) + (b2.x + b3.x);
        t.y = (b0.y + b1.y) + (b2.y + b3.y);
        t.z = (b0.z + b1.z) + (b2.z + b3.z);
        t.w = (b0.w + b1.w) + (b2.w + b3.w);
        bf16x4 o;
        o[0] = (bf16)t.x; o[1] = (bf16)t.y; o[2] = (bf16)t.z; o[3] = (bf16)t.w;
        *(bf16x4*)(dst + r * 256 + tid * 4) = o;
    }
}

// ---------------------------------------------------------------------------
// Kernel 2: NT GEMM  out[m][n] = sum_k A[m][k]*B[n][k] + bias[n]
//   A = xs  (M=4096, K=256) bf16 row-major
//   B = wsT (N=4096, K=256) bf16 row-major
// m97 structure: 128x128 block tile, BK=32, global_load_lds width=16,
// 4 waves in 2x2, each wave 64x64 = 4x4 tiles of 16x16x32 MFMA.
// (unchanged this round — isolating the reduce fix)
// ---------------------------------------------------------------------------
__global__ __launch_bounds__(256) void gemm_bt_kernel(
    const bf16* __restrict__ A, const bf16* __restrict__ B,
    const float* __restrict__ bias, float* __restrict__ out)
{
    __shared__ bf16 As[128 * 32];   // 8 KB
    __shared__ bf16 Bs[128 * 32];   // 8 KB

    const int m0   = blockIdx.y * 128;
    const int n0   = blockIdx.x * 128;
    const int tid  = threadIdx.x;
    const int lane = tid & 63;
    const int w    = tid >> 6;
    const int wm   = (w & 1) * 64;
    const int wn   = (w >> 1) * 64;
    const int l15  = lane & 15;
    const int quad = lane >> 4;

    f32x4 acc[4][4] = {};

    for (int kk = 0; kk < 8; ++kk) {
        const int k0 = kk * 32;
        #pragma unroll
        for (int c = 0; c < 2; ++c) {
            const int chunk = c * 256 + tid;
            const int row   = chunk >> 2;      // 0..127
            const int kc    = chunk & 3;       // 16B chunk within 64B row
            const bf16* ga = A + (m0 + row) * 256 + k0 + kc * 8;
            const bf16* gb = B + (n0 + row) * 256 + k0 + kc * 8;
            __builtin_amdgcn_global_load_lds(
                (const __attribute__((address_space(1))) void*)ga,
                (__attribute__((address_space(3))) void*)(As + chunk * 8), 16, 0, 0);
            __builtin_amdgcn_global_load_lds(
                (const __attribute__((address_space(1))) void*)gb,
                (__attribute__((address_space(3))) void*)(Bs + chunk * 8), 16, 0, 0);
        }
        __syncthreads();

        bf16x8 af[4], bfr[4];
        #pragma unroll
        for (int t = 0; t < 4; ++t) {
            af[t]  = *(const bf16x8*)(As + (wm + t * 16 + l15) * 32 + quad * 8);
            bfr[t] = *(const bf16x8*)(Bs + (wn + t * 16 + l15) * 32 + quad * 8);
        }
        #pragma unroll
        for (int mt = 0; mt < 4; ++mt)
            #pragma unroll
            for (int nt = 0; nt < 4; ++nt)
                acc[mt][nt] = __builtin_amdgcn_mfma_f32_16x16x32_bf16(
                    af[mt], bfr[nt], acc[mt][nt], 0, 0, 0);
        __syncthreads();
    }

    #pragma unroll
    for (int nt = 0; nt < 4; ++nt) {
        const int col = n0 + wn + nt * 16 + l15;
        const float bv = bias[col];
        #pragma unroll
        for (int mt = 0; mt < 4; ++mt) {
            const int rbase = m0 + wm + mt * 16 + quad * 4;
            #pragma unroll
            for (int r = 0; r < 4; ++r)
                out[(rbase + r) * OUT_F + col] = acc[mt][nt][r] + bv;
        }
    }
}

extern "C" void kernel_launch(void* const* d_in, const int* in_sizes, int n_in,
                              void* d_out, int out_size, void* d_ws, size_t ws_size,
                              hipStream_t stream)
{
    const float* x      = (const float*)d_in[0];  // (4096, 4096)
    const float* weight = (const float*)d_in[1];  // (4096, 4096)
    const float* bias   = (const float*)d_in[2];  // (4096,)
    float* out = (float*)d_out;                   // (4096, 4096) f32

    bf16* xs  = (bf16*)d_ws;                      // 4096*256 bf16 = 2 MB
    bf16* wsT = xs + 4096 * 256;                  // 4096*256 bf16 = 2 MB

    reduce_kernel<<<8192, 256, 0, stream>>>(x, weight, xs, wsT);
    gemm_bt_kernel<<<dim3(32, 32), 256, 0, stream>>>(xs, wsT, bias, out);
}